// Round 1
// baseline (66.242 us; speedup 1.0000x reference)
//
#include <hip/hip_runtime.h>

#define BATCH 4096
#define FEAT_DIM 2048
#define NTHREADS 256

__global__ void cl_zero_out(float* out) {
    out[0] = 0.0f;
}

__global__ __launch_bounds__(NTHREADS) void cl_main(
        const float* __restrict__ x,
        const int* __restrict__ labels,
        const float* __restrict__ centers,
        float* __restrict__ out) {
    const int row = blockIdx.x;
    const int tid = threadIdx.x;

    const float4* xr = reinterpret_cast<const float4*>(x + (size_t)row * FEAT_DIM);
    const int lab = labels[row];
    const float4* cr = reinterpret_cast<const float4*>(centers + (size_t)lab * FEAT_DIM);

    float xx = 0.f, cc = 0.f, xc = 0.f;
    // FEAT_DIM/4 = 512 float4 elements, 256 threads -> 2 iterations each.
    #pragma unroll
    for (int j = tid; j < FEAT_DIM / 4; j += NTHREADS) {
        float4 a = xr[j];
        float4 b = cr[j];
        xx += a.x * a.x + a.y * a.y + a.z * a.z + a.w * a.w;
        cc += b.x * b.x + b.y * b.y + b.z * b.z + b.w * b.w;
        xc += a.x * b.x + a.y * b.y + a.z * b.z + a.w * b.w;
    }

    // wave64 butterfly reduce
    #pragma unroll
    for (int off = 32; off > 0; off >>= 1) {
        xx += __shfl_down(xx, off, 64);
        cc += __shfl_down(cc, off, 64);
        xc += __shfl_down(xc, off, 64);
    }

    __shared__ float sxx[NTHREADS / 64], scc[NTHREADS / 64], sxc[NTHREADS / 64];
    const int wave = tid >> 6;
    const int lane = tid & 63;
    if (lane == 0) {
        sxx[wave] = xx;
        scc[wave] = cc;
        sxc[wave] = xc;
    }
    __syncthreads();

    if (tid == 0) {
        float X = 0.f, C = 0.f, K = 0.f;
        #pragma unroll
        for (int w = 0; w < NTHREADS / 64; ++w) {
            X += sxx[w];
            C += scc[w];
            K += sxc[w];
        }
        float dist = X + C - 2.0f * K;
        dist = fminf(fmaxf(dist, 1e-12f), 1e12f);
        atomicAdd(out, dist * (1.0f / BATCH));
    }
}

extern "C" void kernel_launch(void* const* d_in, const int* in_sizes, int n_in,
                              void* d_out, int out_size, void* d_ws, size_t ws_size,
                              hipStream_t stream) {
    const float* x       = (const float*)d_in[0];
    const int*   labels  = (const int*)d_in[1];
    const float* centers = (const float*)d_in[2];
    float*       out     = (float*)d_out;

    cl_zero_out<<<1, 1, 0, stream>>>(out);
    cl_main<<<BATCH, NTHREADS, 0, stream>>>(x, labels, centers, out);
}

// Round 2
// 17.927 us; speedup vs baseline: 3.6952x; 3.6952x over previous
//
#include <hip/hip_runtime.h>

#define BATCH 4096
#define FEAT_DIM 2048
#define NTHREADS 256
#define ROWS_PER_BLOCK 4           // one wave64 per row
#define NBLOCKS (BATCH / ROWS_PER_BLOCK)   // 1024

// Kernel A: one wave per row. dist_row = ||x_row - c_{label}||^2, clamped.
// Per-block sum of 4 rows' dists -> partial[blockIdx].
__global__ __launch_bounds__(NTHREADS) void cl_rows(
        const float* __restrict__ x,
        const int* __restrict__ labels,
        const float* __restrict__ centers,
        float* __restrict__ partial) {
    const int tid  = threadIdx.x;
    const int wave = tid >> 6;
    const int lane = tid & 63;
    const int row  = blockIdx.x * ROWS_PER_BLOCK + wave;

    const int lab = labels[row];
    const float4* __restrict__ xr =
        reinterpret_cast<const float4*>(x + (size_t)row * FEAT_DIM);
    const float4* __restrict__ cr =
        reinterpret_cast<const float4*>(centers + (size_t)lab * FEAT_DIM);

    // 2048 floats / 64 lanes = 8 float4 per lane per array, all independent.
    float4 a[8], b[8];
    #pragma unroll
    for (int k = 0; k < 8; ++k) a[k] = xr[lane + 64 * k];
    #pragma unroll
    for (int k = 0; k < 8; ++k) b[k] = cr[lane + 64 * k];

    float s = 0.f;
    #pragma unroll
    for (int k = 0; k < 8; ++k) {
        float dx = a[k].x - b[k].x;
        float dy = a[k].y - b[k].y;
        float dz = a[k].z - b[k].z;
        float dw = a[k].w - b[k].w;
        s += dx * dx + dy * dy + dz * dz + dw * dw;
    }

    // single-value wave64 reduce
    #pragma unroll
    for (int off = 32; off > 0; off >>= 1) s += __shfl_down(s, off, 64);

    __shared__ float sw[ROWS_PER_BLOCK];
    if (lane == 0) {
        sw[wave] = fminf(fmaxf(s, 1e-12f), 1e12f);
    }
    __syncthreads();

    if (tid == 0) {
        float t = 0.f;
        #pragma unroll
        for (int w = 0; w < ROWS_PER_BLOCK; ++w) t += sw[w];
        partial[blockIdx.x] = t;
    }
}

// Kernel B: reduce NBLOCKS partials, write the mean.
__global__ __launch_bounds__(NTHREADS) void cl_final(
        const float* __restrict__ partial,
        float* __restrict__ out) {
    const int tid = threadIdx.x;
    float s = 0.f;
    #pragma unroll
    for (int i = tid; i < NBLOCKS; i += NTHREADS) s += partial[i];

    #pragma unroll
    for (int off = 32; off > 0; off >>= 1) s += __shfl_down(s, off, 64);

    __shared__ float sw[NTHREADS / 64];
    if ((tid & 63) == 0) sw[tid >> 6] = s;
    __syncthreads();

    if (tid == 0) {
        float t = 0.f;
        #pragma unroll
        for (int w = 0; w < NTHREADS / 64; ++w) t += sw[w];
        out[0] = t * (1.0f / BATCH);
    }
}

extern "C" void kernel_launch(void* const* d_in, const int* in_sizes, int n_in,
                              void* d_out, int out_size, void* d_ws, size_t ws_size,
                              hipStream_t stream) {
    const float* x       = (const float*)d_in[0];
    const int*   labels  = (const int*)d_in[1];
    const float* centers = (const float*)d_in[2];
    float*       out     = (float*)d_out;
    float*       partial = (float*)d_ws;   // NBLOCKS floats = 4 KB

    cl_rows<<<NBLOCKS, NTHREADS, 0, stream>>>(x, labels, centers, partial);
    cl_final<<<1, NTHREADS, 0, stream>>>(partial, out);
}